// Round 2
// baseline (431.076 us; speedup 1.0000x reference)
//
#include <hip/hip_runtime.h>

#define B_SZ 8
#define S_SZ 1024
#define DM   1024
#define NH   16
#define DK   64

typedef __bf16 bf16;
typedef __bf16 bf16x8 __attribute__((ext_vector_type(8)));
typedef float  f32x4  __attribute__((ext_vector_type(4)));

__device__ __forceinline__ f32x4 mfma16x16x32(bf16x8 a, bf16x8 b, f32x4 c) {
    return __builtin_amdgcn_mfma_f32_16x16x32_bf16(a, b, c, 0, 0, 0);
}

typedef const __attribute__((address_space(1))) void* gptr_t;
typedef __attribute__((address_space(3))) void*       sptr_t;
__device__ __forceinline__ void async_cp16(const void* g, void* s) {
    __builtin_amdgcn_global_load_lds((gptr_t)g, (sptr_t)s, 16, 0, 0);
}

// ---------------------------------------------------------------------------
// Kernel 0: fp32 -> bf16 convert for X (z<3) and W (z>=3).
// ---------------------------------------------------------------------------
__global__ __launch_bounds__(256)
void cvt_kernel(const float* __restrict__ x0, const float* __restrict__ x1,
                const float* __restrict__ x2, const float* __restrict__ w0,
                const float* __restrict__ w1, const float* __restrict__ w2,
                bf16* __restrict__ xb, bf16* __restrict__ wb)
{
    const int z = blockIdx.y;
    const float* src;
    bf16* dst;
    int n;
    if (z < 3) {
        src = (z == 0) ? x0 : (z == 1) ? x1 : x2;
        dst = xb + (size_t)z * (8u * 1024 * 1024);
        n = 8 * 1024 * 1024;
    } else {
        const int w = z - 3;
        src = (w == 0) ? w0 : (w == 1) ? w1 : w2;
        dst = wb + (size_t)w * (1024 * 1024);
        n = 1024 * 1024;
    }
    const int idx = (blockIdx.x * 256 + threadIdx.x) * 8;
    if (idx >= n) return;
    const float4 a = *(const float4*)(src + idx);
    const float4 c = *(const float4*)(src + idx + 4);
    union { bf16 h[8]; uint4 u; } pk;
    pk.h[0] = (bf16)a.x; pk.h[1] = (bf16)a.y; pk.h[2] = (bf16)a.z; pk.h[3] = (bf16)a.w;
    pk.h[4] = (bf16)c.x; pk.h[5] = (bf16)c.y; pk.h[6] = (bf16)c.z; pk.h[7] = (bf16)c.w;
    *(uint4*)(dst + idx) = pk.u;
}

// gp fp32 -> bf16 (runs AFTER qkv_gemm; output aliases the dead xb region)
__global__ __launch_bounds__(256)
void cvt_gp_kernel(const float* __restrict__ gp, bf16* __restrict__ gpb)
{
    const int idx = (blockIdx.x * 256 + threadIdx.x) * 8;
    const float4 a = *(const float4*)(gp + idx);
    const float4 c = *(const float4*)(gp + idx + 4);
    union { bf16 h[8]; uint4 u; } pk;
    pk.h[0] = (bf16)a.x; pk.h[1] = (bf16)a.y; pk.h[2] = (bf16)a.z; pk.h[3] = (bf16)a.w;
    pk.h[4] = (bf16)c.x; pk.h[5] = (bf16)c.y; pk.h[6] = (bf16)c.z; pk.h[7] = (bf16)c.w;
    *(uint4*)(gpb + idx) = pk.u;
}

// ---------------------------------------------------------------------------
// Kernel 1: m97-style bf16 GEMM with XOR chunk-swizzled LDS (unchanged).
// ---------------------------------------------------------------------------
__global__ __launch_bounds__(256, 2)
void qkv_gemm(const bf16* __restrict__ xb, const bf16* __restrict__ wb,
              const float* __restrict__ bq, const float* __restrict__ bk,
              const float* __restrict__ bv,
              bf16* __restrict__ qb, bf16* __restrict__ kb,
              bf16* __restrict__ vb)
{
    const int z = blockIdx.z;
    const bf16* A  = xb + (size_t)z * (8u * 1024 * 1024);
    const bf16* Bm = wb + (size_t)z * (1024 * 1024);
    const float* bias = (z == 0) ? bq : (z == 1) ? bk : bv;

    __shared__ bf16 Ash[128 * 64];
    __shared__ bf16 Bsh[128 * 64];

    const int tid  = threadIdx.x;
    const int wid  = tid >> 6;
    const int lane = tid & 63;
    const int quad = lane >> 4;
    const int l16  = lane & 15;
    const int wm   = wid >> 1, wn = wid & 1;
    const int bm   = blockIdx.x, bn = blockIdx.y;

    f32x4 acc[4][4] = {};

    for (int k0 = 0; k0 < DM; k0 += 64) {
        __syncthreads();
        #pragma unroll
        for (int i = 0; i < 4; ++i) {
            const int e   = (i * 256 + tid) * 8;
            const int row = e >> 6;
            const int c   = ((e >> 3) & 7) ^ (row & 7);   // source-chunk swizzle
            async_cp16(A  + (size_t)(bm * 128 + row) * DM + k0 + c * 8, &Ash[e]);
            async_cp16(Bm + (size_t)(bn * 128 + row) * DM + k0 + c * 8, &Bsh[e]);
        }
        __syncthreads();

        #pragma unroll
        for (int ks = 0; ks < 2; ++ks) {
            bf16x8 af[4], bfr[4];
            #pragma unroll
            for (int mi = 0; mi < 4; ++mi) {
                const int row = wm * 64 + mi * 16 + l16;
                af[mi] = *(const bf16x8*)&Ash[row * 64 + (((ks * 4 + quad) ^ (l16 & 7)) << 3)];
            }
            #pragma unroll
            for (int ni = 0; ni < 4; ++ni) {
                const int row = wn * 64 + ni * 16 + l16;
                bfr[ni] = *(const bf16x8*)&Bsh[row * 64 + (((ks * 4 + quad) ^ (l16 & 7)) << 3)];
            }
            #pragma unroll
            for (int mi = 0; mi < 4; ++mi)
                #pragma unroll
                for (int ni = 0; ni < 4; ++ni)
                    acc[mi][ni] = mfma16x16x32(af[mi], bfr[ni], acc[mi][ni]);
        }
    }

    #pragma unroll
    for (int ni = 0; ni < 4; ++ni) {
        const int n    = bn * 128 + wn * 64 + ni * 16 + l16;
        const float bv_ = bias[n];
        const int h = n >> 6, d = n & 63;
        #pragma unroll
        for (int mi = 0; mi < 4; ++mi) {
            const int m0 = bm * 128 + wm * 64 + mi * 16 + quad * 4;
            const int b  = m0 >> 10;
            const int s0 = m0 & 1023;
            if (z == 2) {
                union { bf16 h4[4]; uint2 u; } pk;
                #pragma unroll
                for (int r = 0; r < 4; ++r) pk.h4[r] = (bf16)(acc[mi][ni][r] + bv_);
                *(uint2*)(vb + ((size_t)((b * NH + h) * DK + d)) * S_SZ + s0) = pk.u;
            } else {
                bf16* dst      = (z == 0) ? qb : kb;
                const float sc = (z == 0) ? 0.125f : 1.0f;
                #pragma unroll
                for (int r = 0; r < 4; ++r)
                    dst[((size_t)(b * NH + h) * S_SZ + (s0 + r)) * DK + d] =
                        (bf16)((acc[mi][ni][r] + bv_) * sc);
            }
        }
    }
}

// ---------------------------------------------------------------------------
// Kernel 2: attention, barrier-free main loop.
//   - 4 waves x disjoint 256-key ranges; partial O/L add (no softmax max, so
//     key-splits are associative).
//   - K/V/gp/Q fragments read directly from global (L2-resident: K,V are
//     128 KB per (b,h), reused by 16 q-blocks) -- no K/V LDS staging, no
//     __syncthreads in the main loop.
//   - P quad-realignment via wave-private 5 KB LDS (LDP=40: 16B-aligned rows,
//     conflict-free uint2 writes / 2-way-free b128 reads).
//   - End: 3-barrier cross-wave O reduction in LDS reusing the dead P space.
// ---------------------------------------------------------------------------
__global__ __launch_bounds__(256, 3)
void attn_kernel(const bf16* __restrict__ qb, const bf16* __restrict__ kb,
                 const bf16* __restrict__ vb, const bf16* __restrict__ gpb,
                 float* __restrict__ out)
{
    __shared__ float Lsh[4][4][16];               // 1 KB
    __shared__ union SMem {
        bf16  P[4][64 * 40];                      // per-wave P bounce, 20 KB
        float O[2][64][68];                       // reduction buffers, 34 KB
    } sm;

    const int tid  = threadIdx.x;
    const int wid  = tid >> 6;
    const int lane = tid & 63;
    const int quad = lane >> 4;
    const int l16  = lane & 15;

    const int bh = blockIdx.x;
    const int qt = blockIdx.y;
    const int b  = bh >> 4;
    const int h  = bh & (NH - 1);
    const int q0 = qt * 64;

    // Q fragments (B-operand of S^T = K*Q^T): qf[m][ks] = Q[q0+m*16+l16][ks*32+quad*8 ..]
    const bf16* qbase = qb + ((size_t)bh * S_SZ + q0) * DK;
    bf16x8 qf[4][2];
    #pragma unroll
    for (int m = 0; m < 4; ++m) {
        const bf16* qr = qbase + (m * 16 + l16) * DK + quad * 8;
        qf[m][0] = *(const bf16x8*)(qr);
        qf[m][1] = *(const bf16x8*)(qr + 32);
    }

    const int key0 = wid * 256;                                   // wave's key range
    const bf16* kbase  = kb  + (size_t)bh * (S_SZ * DK) + (size_t)key0 * DK;
    const bf16* vbase  = vb  + (size_t)bh * (DK * S_SZ);          // [d][s]
    const bf16* gpbase = gpb + ((size_t)b * S_SZ + q0) * S_SZ + key0;

    f32x4 acc[4][4] = {};   // acc[m][n]: q = m*16+quad*4+r, d = n*16+l16
    float lp[4] = {};       // partial denom for q = m*16+l16 (this wave's keys)

    bf16* Pw = sm.P[wid];

    #pragma unroll 2
    for (int kc = 0; kc < 8; ++kc) {
        const int kb0 = kc * 32;

        // K fragments (A-operand): K[key0+kb0+kt2*16+l16][ks*32+quad*8 ..]
        bf16x8 kf[2][2];
        #pragma unroll
        for (int kt2 = 0; kt2 < 2; ++kt2) {
            const bf16* kr = kbase + (size_t)(kb0 + kt2 * 16 + l16) * DK + quad * 8;
            kf[kt2][0] = *(const bf16x8*)(kr);
            kf[kt2][1] = *(const bf16x8*)(kr + 32);
        }
        // gp: lane covers keys kt2*16+quad*4..+3 for q = m*16+l16
        ushort4 gpl[4][2];
        #pragma unroll
        for (int m = 0; m < 4; ++m)
            #pragma unroll
            for (int kt2 = 0; kt2 < 2; ++kt2)
                gpl[m][kt2] = *(const ushort4*)(gpbase + (size_t)(m * 16 + l16) * S_SZ
                                                + kb0 + kt2 * 16 + quad * 4);
        // V fragments (B-operand, issued early): V[key0+kb0+quad*8..][n*16+l16]
        bf16x8 vf[4];
        #pragma unroll
        for (int n = 0; n < 4; ++n)
            vf[n] = *(const bf16x8*)(vbase + (size_t)(n * 16 + l16) * S_SZ
                                     + key0 + kb0 + quad * 8);

        // S^T, exp, *gp, pack -> Pw  (C layout: col(l16)=q, row(quad*4+r)=key)
        #pragma unroll
        for (int m = 0; m < 4; ++m) {
            #pragma unroll
            for (int kt2 = 0; kt2 < 2; ++kt2) {
                f32x4 s = {0.0f, 0.0f, 0.0f, 0.0f};
                s = mfma16x16x32(kf[kt2][0], qf[m][0], s);
                s = mfma16x16x32(kf[kt2][1], qf[m][1], s);
                union { bf16 h4[4]; uint2 u; } pk;
                const unsigned short* gu = (const unsigned short*)&gpl[m][kt2];
                #pragma unroll
                for (int r = 0; r < 4; ++r) {
                    const float pv = __expf(s[r]);
                    lp[m] += pv;
                    const float g = __uint_as_float(((unsigned)gu[r]) << 16);
                    pk.h4[r] = (bf16)(pv * g);
                }
                *(uint2*)&Pw[(m * 16 + l16) * 40 + kt2 * 16 + quad * 4] = pk.u;
            }
        }

        // PV: A = P[q=l16][k=quad*8..], B = vf  (wave-private LDS, lgkmcnt-ordered)
        #pragma unroll
        for (int m = 0; m < 4; ++m) {
            const bf16x8 pf = *(const bf16x8*)&Pw[(m * 16 + l16) * 40 + quad * 8];
            #pragma unroll
            for (int n = 0; n < 4; ++n)
                acc[m][n] = mfma16x16x32(pf, vf[n], acc[m][n]);
        }
    }

    // denominator: sum across quads (keys) within wave, publish per-wave partial
    #pragma unroll
    for (int m = 0; m < 4; ++m) {
        lp[m] += __shfl_xor(lp[m], 16, 64);
        lp[m] += __shfl_xor(lp[m], 32, 64);
    }
    if (quad == 0) {
        #pragma unroll
        for (int m = 0; m < 4; ++m) Lsh[wid][m][l16] = lp[m];
    }
    __syncthreads();   // Lsh ready; P space dead -> reuse as O buffers

    float (*OA)[68] = sm.O[0];
    float (*OB)[68] = sm.O[1];
    if (wid & 1) {     // waves 1,3 seed the two buffers
        float (*O)[68] = (wid == 1) ? OA : OB;
        #pragma unroll
        for (int m = 0; m < 4; ++m)
            #pragma unroll
            for (int n = 0; n < 4; ++n)
                #pragma unroll
                for (int r = 0; r < 4; ++r)
                    O[m * 16 + quad * 4 + r][n * 16 + l16] = acc[m][n][r];
    }
    __syncthreads();
    if (!(wid & 1)) {  // waves 0,2 accumulate
        float (*O)[68] = (wid == 0) ? OA : OB;
        #pragma unroll
        for (int m = 0; m < 4; ++m)
            #pragma unroll
            for (int n = 0; n < 4; ++n)
                #pragma unroll
                for (int r = 0; r < 4; ++r)
                    O[m * 16 + quad * 4 + r][n * 16 + l16] += acc[m][n][r];
    }
    __syncthreads();

    // final: wave w handles q rows w*16..+15; lane (rr = lane>>2) x 4 float4s
    const int rr  = lane >> 2;
    const int row = wid * 16 + rr;
    const float invl = 1.0f / (Lsh[0][wid][rr] + Lsh[1][wid][rr] +
                               Lsh[2][wid][rr] + Lsh[3][wid][rr]);
    float* orow = out + ((size_t)b * S_SZ + q0 + row) * DM + h * DK;
    #pragma unroll
    for (int c = 0; c < 4; ++c) {
        const int col = c * 16 + (lane & 3) * 4;
        const float4 a4 = *(const float4*)&OA[row][col];
        const float4 b4 = *(const float4*)&OB[row][col];
        float4 o;
        o.x = (a4.x + b4.x) * invl;
        o.y = (a4.y + b4.y) * invl;
        o.z = (a4.z + b4.z) * invl;
        o.w = (a4.w + b4.w) * invl;
        *(float4*)(orow + col) = o;
    }
}

extern "C" void kernel_launch(void* const* d_in, const int* in_sizes, int n_in,
                              void* d_out, int out_size, void* d_ws, size_t ws_size,
                              hipStream_t stream) {
    const float* queries = (const float*)d_in[0];
    const float* keys    = (const float*)d_in[1];
    const float* values  = (const float*)d_in[2];
    const float* gp      = (const float*)d_in[3];
    // d_in[4] attention_mask: dead code in reference
    const float* Wq = (const float*)d_in[5];
    const float* bq = (const float*)d_in[6];
    const float* Wk = (const float*)d_in[7];
    const float* bk = (const float*)d_in[8];
    const float* Wv = (const float*)d_in[9];
    const float* bv = (const float*)d_in[10];
    float* out = (float*)d_out;

    // ws (bf16 elems): Xb 3x8M | Wb 3x1M | qb,kb,vb 3x8M. gpb reuses xb
    // (xb is dead after qkv_gemm; cvt_gp runs after it in stream order).
    bf16* xb = (bf16*)d_ws;
    bf16* wb = xb + (size_t)3 * 8 * 1024 * 1024;
    bf16* qb = wb + (size_t)3 * 1024 * 1024;
    bf16* kb = qb + (size_t)B_SZ * NH * S_SZ * DK;
    bf16* vb = kb + (size_t)B_SZ * NH * S_SZ * DK;
    bf16* gpb = xb;
    (void)ws_size; (void)in_sizes; (void)n_in; (void)out_size;

    dim3 gc(4096, 6);
    cvt_kernel<<<gc, 256, 0, stream>>>(queries, keys, values, Wq, Wk, Wv, xb, wb);

    dim3 g1(64, 8, 3);
    qkv_gemm<<<g1, 256, 0, stream>>>(xb, wb, bq, bk, bv, qb, kb, vb);

    cvt_gp_kernel<<<dim3(4096), 256, 0, stream>>>(gp, gpb);

    dim3 g2(B_SZ * NH /*128*/, S_SZ / 64 /*16*/, 1);
    attn_kernel<<<g2, 256, 0, stream>>>(qb, kb, vb, gpb, out);
}

// Round 3
// 354.292 us; speedup vs baseline: 1.2167x; 1.2167x over previous
//
#include <hip/hip_runtime.h>

#define B_SZ 8
#define S_SZ 1024
#define DM   1024
#define NH   16
#define DK   64

typedef __bf16 bf16;
typedef __bf16 bf16x8 __attribute__((ext_vector_type(8)));
typedef float  f32x4  __attribute__((ext_vector_type(4)));

__device__ __forceinline__ f32x4 mfma16x16x32(bf16x8 a, bf16x8 b, f32x4 c) {
    return __builtin_amdgcn_mfma_f32_16x16x32_bf16(a, b, c, 0, 0, 0);
}

typedef const __attribute__((address_space(1))) void* gptr_t;
typedef __attribute__((address_space(3))) void*       sptr_t;
__device__ __forceinline__ void async_cp16(const void* g, void* s) {
    __builtin_amdgcn_global_load_lds((gptr_t)g, (sptr_t)s, 16, 0, 0);
}

// ---------------------------------------------------------------------------
// Kernel 0: fp32 -> bf16 convert for X (z<3) and W (z>=3).
// ---------------------------------------------------------------------------
__global__ __launch_bounds__(256)
void cvt_kernel(const float* __restrict__ x0, const float* __restrict__ x1,
                const float* __restrict__ x2, const float* __restrict__ w0,
                const float* __restrict__ w1, const float* __restrict__ w2,
                bf16* __restrict__ xb, bf16* __restrict__ wb)
{
    const int z = blockIdx.y;
    const float* src;
    bf16* dst;
    int n;
    if (z < 3) {
        src = (z == 0) ? x0 : (z == 1) ? x1 : x2;
        dst = xb + (size_t)z * (8u * 1024 * 1024);
        n = 8 * 1024 * 1024;
    } else {
        const int w = z - 3;
        src = (w == 0) ? w0 : (w == 1) ? w1 : w2;
        dst = wb + (size_t)w * (1024 * 1024);
        n = 1024 * 1024;
    }
    const int idx = (blockIdx.x * 256 + threadIdx.x) * 8;
    if (idx >= n) return;
    const float4 a = *(const float4*)(src + idx);
    const float4 c = *(const float4*)(src + idx + 4);
    union { bf16 h[8]; uint4 u; } pk;
    pk.h[0] = (bf16)a.x; pk.h[1] = (bf16)a.y; pk.h[2] = (bf16)a.z; pk.h[3] = (bf16)a.w;
    pk.h[4] = (bf16)c.x; pk.h[5] = (bf16)c.y; pk.h[6] = (bf16)c.z; pk.h[7] = (bf16)c.w;
    *(uint4*)(dst + idx) = pk.u;
}

// gp fp32 -> bf16 (runs AFTER qkv_gemm; output aliases the dead xb region)
__global__ __launch_bounds__(256)
void cvt_gp_kernel(const float* __restrict__ gp, bf16* __restrict__ gpb)
{
    const int idx = (blockIdx.x * 256 + threadIdx.x) * 8;
    const float4 a = *(const float4*)(gp + idx);
    const float4 c = *(const float4*)(gp + idx + 4);
    union { bf16 h[8]; uint4 u; } pk;
    pk.h[0] = (bf16)a.x; pk.h[1] = (bf16)a.y; pk.h[2] = (bf16)a.z; pk.h[3] = (bf16)a.w;
    pk.h[4] = (bf16)c.x; pk.h[5] = (bf16)c.y; pk.h[6] = (bf16)c.z; pk.h[7] = (bf16)c.w;
    *(uint4*)(gpb + idx) = pk.u;
}

// ---------------------------------------------------------------------------
// Kernel 1: m97-style bf16 GEMM with XOR chunk-swizzled LDS (unchanged).
// ---------------------------------------------------------------------------
__global__ __launch_bounds__(256, 2)
void qkv_gemm(const bf16* __restrict__ xb, const bf16* __restrict__ wb,
              const float* __restrict__ bq, const float* __restrict__ bk,
              const float* __restrict__ bv,
              bf16* __restrict__ qb, bf16* __restrict__ kb,
              bf16* __restrict__ vb)
{
    const int z = blockIdx.z;
    const bf16* A  = xb + (size_t)z * (8u * 1024 * 1024);
    const bf16* Bm = wb + (size_t)z * (1024 * 1024);
    const float* bias = (z == 0) ? bq : (z == 1) ? bk : bv;

    __shared__ bf16 Ash[128 * 64];
    __shared__ bf16 Bsh[128 * 64];

    const int tid  = threadIdx.x;
    const int wid  = tid >> 6;
    const int lane = tid & 63;
    const int quad = lane >> 4;
    const int l16  = lane & 15;
    const int wm   = wid >> 1, wn = wid & 1;
    const int bm   = blockIdx.x, bn = blockIdx.y;

    f32x4 acc[4][4] = {};

    for (int k0 = 0; k0 < DM; k0 += 64) {
        __syncthreads();
        #pragma unroll
        for (int i = 0; i < 4; ++i) {
            const int e   = (i * 256 + tid) * 8;
            const int row = e >> 6;
            const int c   = ((e >> 3) & 7) ^ (row & 7);   // source-chunk swizzle
            async_cp16(A  + (size_t)(bm * 128 + row) * DM + k0 + c * 8, &Ash[e]);
            async_cp16(Bm + (size_t)(bn * 128 + row) * DM + k0 + c * 8, &Bsh[e]);
        }
        __syncthreads();

        #pragma unroll
        for (int ks = 0; ks < 2; ++ks) {
            bf16x8 af[4], bfr[4];
            #pragma unroll
            for (int mi = 0; mi < 4; ++mi) {
                const int row = wm * 64 + mi * 16 + l16;
                af[mi] = *(const bf16x8*)&Ash[row * 64 + (((ks * 4 + quad) ^ (l16 & 7)) << 3)];
            }
            #pragma unroll
            for (int ni = 0; ni < 4; ++ni) {
                const int row = wn * 64 + ni * 16 + l16;
                bfr[ni] = *(const bf16x8*)&Bsh[row * 64 + (((ks * 4 + quad) ^ (l16 & 7)) << 3)];
            }
            #pragma unroll
            for (int mi = 0; mi < 4; ++mi)
                #pragma unroll
                for (int ni = 0; ni < 4; ++ni)
                    acc[mi][ni] = mfma16x16x32(af[mi], bfr[ni], acc[mi][ni]);
        }
    }

    #pragma unroll
    for (int ni = 0; ni < 4; ++ni) {
        const int n    = bn * 128 + wn * 64 + ni * 16 + l16;
        const float bv_ = bias[n];
        const int h = n >> 6, d = n & 63;
        #pragma unroll
        for (int mi = 0; mi < 4; ++mi) {
            const int m0 = bm * 128 + wm * 64 + mi * 16 + quad * 4;
            const int b  = m0 >> 10;
            const int s0 = m0 & 1023;
            if (z == 2) {
                union { bf16 h4[4]; uint2 u; } pk;
                #pragma unroll
                for (int r = 0; r < 4; ++r) pk.h4[r] = (bf16)(acc[mi][ni][r] + bv_);
                *(uint2*)(vb + ((size_t)((b * NH + h) * DK + d)) * S_SZ + s0) = pk.u;
            } else {
                bf16* dst      = (z == 0) ? qb : kb;
                const float sc = (z == 0) ? 0.125f : 1.0f;
                #pragma unroll
                for (int r = 0; r < 4; ++r)
                    dst[((size_t)(b * NH + h) * S_SZ + (s0 + r)) * DK + d] =
                        (bf16)((acc[mi][ni][r] + bv_) * sc);
            }
        }
    }
}

// ---------------------------------------------------------------------------
// Kernel 2: attention — round-0 structure (waves split over q, LDS-staged K/V,
// per-wave P bounce) with a T3-min software pipeline:
//   - 64-key tiles, DOUBLE-buffered K/V LDS (16+16 KB; total 42 KB -> 3 blk/CU)
//   - each iteration issues tile t+1's global_load_lds + gp register loads
//     BEFORE computing tile t; ONE barrier per tile at the end, so the
//     implicit vmcnt(0) drain lands after a full compute phase of overlap
//     (round-0 drained immediately after issue -> exposed full latency).
//   - explicit 2x unrolled ping-pong (static buffer indices, named gplA/gplB).
// ---------------------------------------------------------------------------
__global__ __launch_bounds__(256, 3)
void attn_kernel(const bf16* __restrict__ qb, const bf16* __restrict__ kb,
                 const bf16* __restrict__ vb, const bf16* __restrict__ gpb,
                 float* __restrict__ out)
{
    __shared__ bf16 Ksh[2][64 * 64];   // [key][dim], chunk-swizzled, 8 KB each
    __shared__ bf16 Vsh[2][64 * 64];   // [dim][key], chunk-swizzled, 8 KB each
    __shared__ bf16 Psh[4][16 * 72];   // per-wave P, [q][key], +8 pad
    __shared__ float Lsh[4][16];

    const int tid  = threadIdx.x;
    const int wid  = tid >> 6;
    const int lane = tid & 63;
    const int quad = lane >> 4;
    const int l16  = lane & 15;

    const int bh = blockIdx.x;
    const int qt = blockIdx.y;
    const int b  = bh >> 4;
    const int h  = bh & (NH - 1);
    const int q0 = qt * 64 + wid * 16;

    // Q as B-operand: B[k=d][n=q]: lane l16 -> q, quad*8+j -> d
    const bf16* qr = qb + ((size_t)bh * S_SZ + q0 + l16) * DK;
    const bf16x8 qf0 = *(const bf16x8*)(qr + quad * 8);
    const bf16x8 qf1 = *(const bf16x8*)(qr + 32 + quad * 8);

    f32x4 acc[4] = {};
    float lpart = 0.0f;

    const bf16* gpq = gpb + ((size_t)b * S_SZ + q0 + l16) * S_SZ;  // gp row q
    const bf16* kbh = kb + (size_t)bh * (S_SZ * DK);
    const bf16* vbh = vb + (size_t)bh * ((size_t)DK * S_SZ);

    // stage tile t (keys t*64..+63) into buffer bufi (compile-time bufi)
    auto STAGE = [&](int t, int bufi) {
        #pragma unroll
        for (int i = 0; i < 2; ++i) {          // K: 64 x 64
            const int e   = (i * 256 + tid) * 8;
            const int row = e >> 6;
            const int c   = ((e >> 3) & 7) ^ (row & 7);
            async_cp16(kbh + (size_t)(t * 64 + row) * DK + c * 8, &Ksh[bufi][e]);
        }
        #pragma unroll
        for (int i = 0; i < 2; ++i) {          // V^T: 64 d x 64 keys
            const int e   = (i * 256 + tid) * 8;
            const int row = e >> 6;
            const int c   = ((e >> 3) & 7) ^ (row & 7);
            async_cp16(vbh + (size_t)row * S_SZ + t * 64 + c * 8, &Vsh[bufi][e]);
        }
    };
    auto GPLOAD = [&](int t, ushort4 (&g)[4]) {
        #pragma unroll
        for (int nb = 0; nb < 4; ++nb)
            g[nb] = *(const ushort4*)(gpq + t * 64 + nb * 16 + quad * 4);
    };
    auto COMPUTE = [&](const bf16* Kb, const bf16* Vb, const ushort4 (&g)[4]) {
        // S^T = K Q^T: lane holds key = nb*16+quad*4+r, q = l16
        f32x4 sc[4];
        #pragma unroll
        for (int nb = 0; nb < 4; ++nb) {
            const int row = nb * 16 + l16;
            const bf16x8 kf0 = *(const bf16x8*)&Kb[row * 64 + ((quad ^ (l16 & 7)) << 3)];
            const bf16x8 kf1 = *(const bf16x8*)&Kb[row * 64 + (((4 + quad) ^ (l16 & 7)) << 3)];
            f32x4 s = {0.0f, 0.0f, 0.0f, 0.0f};
            s = mfma16x16x32(kf0, qf0, s);
            s = mfma16x16x32(kf1, qf1, s);
            sc[nb] = s;
        }
        // p = exp(s), denominator partial, P*gp -> Psh packed
        #pragma unroll
        for (int nb = 0; nb < 4; ++nb) {
            union { bf16 h4[4]; uint2 u; } pk;
            const unsigned short* gu = (const unsigned short*)&g[nb];
            #pragma unroll
            for (int r = 0; r < 4; ++r) {
                const float pv = __expf(sc[nb][r]);
                lpart += pv;
                const float gg = __uint_as_float(((unsigned)gu[r]) << 16);
                pk.h4[r] = (bf16)(pv * gg);
            }
            *(uint2*)&Psh[wid][l16 * 72 + nb * 16 + quad * 4] = pk.u;
        }
        // PV: A = P[q=l16][k], B = V^T
        bf16x8 pf[2];
        #pragma unroll
        for (int j = 0; j < 2; ++j)
            pf[j] = *(const bf16x8*)&Psh[wid][l16 * 72 + j * 32 + quad * 8];
        #pragma unroll
        for (int ni = 0; ni < 4; ++ni) {
            const int vrow = ni * 16 + l16;
            #pragma unroll
            for (int j = 0; j < 2; ++j) {
                const bf16x8 vf =
                    *(const bf16x8*)&Vb[vrow * 64 + (((j * 4 + quad) ^ (l16 & 7)) << 3)];
                acc[ni] = mfma16x16x32(pf[j], vf, acc[ni]);
            }
        }
    };

    ushort4 gplA[4], gplB[4];
    STAGE(0, 0);
    GPLOAD(0, gplA);
    __syncthreads();                       // prologue drain (once)

    for (int tt = 0; tt < 8; ++tt) {
        const int t0 = tt * 2;
        // half A: prefetch t0+1 into buf1, compute t0 from buf0
        STAGE(t0 + 1, 1);
        GPLOAD(t0 + 1, gplB);
        COMPUTE(Ksh[0], Vsh[0], gplA);
        __syncthreads();                   // drain lands after compute overlap
        // half B: prefetch t0+2 into buf0, compute t0+1 from buf1
        if (t0 + 2 < 16) {
            STAGE(t0 + 2, 0);
            GPLOAD(t0 + 2, gplA);
        }
        COMPUTE(Ksh[1], Vsh[1], gplB);
        __syncthreads();
    }

    // denominator: sum across quads (keys), broadcast via LDS
    lpart += __shfl_xor(lpart, 16, 64);
    lpart += __shfl_xor(lpart, 32, 64);
    if (quad == 0) Lsh[wid][l16] = 1.0f / lpart;
    __syncthreads();

    #pragma unroll
    for (int r = 0; r < 4; ++r) {
        const float inv = Lsh[wid][quad * 4 + r];
        float* orow = out + ((size_t)b * S_SZ + q0 + quad * 4 + r) * DM + h * DK;
        #pragma unroll
        for (int ni = 0; ni < 4; ++ni)
            orow[ni * 16 + l16] = acc[ni][r] * inv;
    }
}

extern "C" void kernel_launch(void* const* d_in, const int* in_sizes, int n_in,
                              void* d_out, int out_size, void* d_ws, size_t ws_size,
                              hipStream_t stream) {
    const float* queries = (const float*)d_in[0];
    const float* keys    = (const float*)d_in[1];
    const float* values  = (const float*)d_in[2];
    const float* gp      = (const float*)d_in[3];
    // d_in[4] attention_mask: dead code in reference
    const float* Wq = (const float*)d_in[5];
    const float* bq = (const float*)d_in[6];
    const float* Wk = (const float*)d_in[7];
    const float* bk = (const float*)d_in[8];
    const float* Wv = (const float*)d_in[9];
    const float* bv = (const float*)d_in[10];
    float* out = (float*)d_out;

    // ws (bf16 elems): Xb 3x8M | Wb 3x1M | qb,kb,vb 3x8M. gpb reuses xb
    // (xb is dead after qkv_gemm; cvt_gp runs after it in stream order).
    bf16* xb = (bf16*)d_ws;
    bf16* wb = xb + (size_t)3 * 8 * 1024 * 1024;
    bf16* qb = wb + (size_t)3 * 1024 * 1024;
    bf16* kb = qb + (size_t)B_SZ * NH * S_SZ * DK;
    bf16* vb = kb + (size_t)B_SZ * NH * S_SZ * DK;
    bf16* gpb = xb;
    (void)ws_size; (void)in_sizes; (void)n_in; (void)out_size;

    dim3 gc(4096, 6);
    cvt_kernel<<<gc, 256, 0, stream>>>(queries, keys, values, Wq, Wk, Wv, xb, wb);

    dim3 g1(64, 8, 3);
    qkv_gemm<<<g1, 256, 0, stream>>>(xb, wb, bq, bk, bv, qb, kb, vb);

    cvt_gp_kernel<<<dim3(4096), 256, 0, stream>>>(gp, gpb);

    dim3 g2(B_SZ * NH /*128*/, S_SZ / 64 /*16*/, 1);
    attn_kernel<<<g2, 256, 0, stream>>>(qb, kb, vb, gpb, out);
}

// Round 4
// 352.766 us; speedup vs baseline: 1.2220x; 1.0043x over previous
//
#include <hip/hip_runtime.h>

#define B_SZ 8
#define S_SZ 1024
#define DM   1024
#define NH   16
#define DK   64

typedef __bf16 bf16;
typedef __bf16 bf16x8 __attribute__((ext_vector_type(8)));
typedef float  f32x4  __attribute__((ext_vector_type(4)));

__device__ __forceinline__ f32x4 mfma16x16x32(bf16x8 a, bf16x8 b, f32x4 c) {
    return __builtin_amdgcn_mfma_f32_16x16x32_bf16(a, b, c, 0, 0, 0);
}

typedef const __attribute__((address_space(1))) void* gptr_t;
typedef __attribute__((address_space(3))) void*       sptr_t;
__device__ __forceinline__ void async_cp16(const void* g, void* s) {
    __builtin_amdgcn_global_load_lds((gptr_t)g, (sptr_t)s, 16, 0, 0);
}

// ---------------------------------------------------------------------------
// Kernel 0: fp32 -> bf16 convert for X (z<3) and W (z>=3).
// ---------------------------------------------------------------------------
__global__ __launch_bounds__(256)
void cvt_kernel(const float* __restrict__ x0, const float* __restrict__ x1,
                const float* __restrict__ x2, const float* __restrict__ w0,
                const float* __restrict__ w1, const float* __restrict__ w2,
                bf16* __restrict__ xb, bf16* __restrict__ wb)
{
    const int z = blockIdx.y;
    const float* src;
    bf16* dst;
    int n;
    if (z < 3) {
        src = (z == 0) ? x0 : (z == 1) ? x1 : x2;
        dst = xb + (size_t)z * (8u * 1024 * 1024);
        n = 8 * 1024 * 1024;
    } else {
        const int w = z - 3;
        src = (w == 0) ? w0 : (w == 1) ? w1 : w2;
        dst = wb + (size_t)w * (1024 * 1024);
        n = 1024 * 1024;
    }
    const int idx = (blockIdx.x * 256 + threadIdx.x) * 8;
    if (idx >= n) return;
    const float4 a = *(const float4*)(src + idx);
    const float4 c = *(const float4*)(src + idx + 4);
    union { bf16 h[8]; uint4 u; } pk;
    pk.h[0] = (bf16)a.x; pk.h[1] = (bf16)a.y; pk.h[2] = (bf16)a.z; pk.h[3] = (bf16)a.w;
    pk.h[4] = (bf16)c.x; pk.h[5] = (bf16)c.y; pk.h[6] = (bf16)c.z; pk.h[7] = (bf16)c.w;
    *(uint4*)(dst + idx) = pk.u;
}

// gp fp32 -> bf16 (runs AFTER qkv_gemm; output aliases the dead xb region)
__global__ __launch_bounds__(256)
void cvt_gp_kernel(const float* __restrict__ gp, bf16* __restrict__ gpb)
{
    const int idx = (blockIdx.x * 256 + threadIdx.x) * 8;
    const float4 a = *(const float4*)(gp + idx);
    const float4 c = *(const float4*)(gp + idx + 4);
    union { bf16 h[8]; uint4 u; } pk;
    pk.h[0] = (bf16)a.x; pk.h[1] = (bf16)a.y; pk.h[2] = (bf16)a.z; pk.h[3] = (bf16)a.w;
    pk.h[4] = (bf16)c.x; pk.h[5] = (bf16)c.y; pk.h[6] = (bf16)c.z; pk.h[7] = (bf16)c.w;
    *(uint4*)(gpb + idx) = pk.u;
}

// ---------------------------------------------------------------------------
// Kernel 1: m97-style bf16 GEMM with XOR chunk-swizzled LDS (unchanged).
// ---------------------------------------------------------------------------
__global__ __launch_bounds__(256, 2)
void qkv_gemm(const bf16* __restrict__ xb, const bf16* __restrict__ wb,
              const float* __restrict__ bq, const float* __restrict__ bk,
              const float* __restrict__ bv,
              bf16* __restrict__ qb, bf16* __restrict__ kb,
              bf16* __restrict__ vb)
{
    const int z = blockIdx.z;
    const bf16* A  = xb + (size_t)z * (8u * 1024 * 1024);
    const bf16* Bm = wb + (size_t)z * (1024 * 1024);
    const float* bias = (z == 0) ? bq : (z == 1) ? bk : bv;

    __shared__ bf16 Ash[128 * 64];
    __shared__ bf16 Bsh[128 * 64];

    const int tid  = threadIdx.x;
    const int wid  = tid >> 6;
    const int lane = tid & 63;
    const int quad = lane >> 4;
    const int l16  = lane & 15;
    const int wm   = wid >> 1, wn = wid & 1;
    const int bm   = blockIdx.x, bn = blockIdx.y;

    f32x4 acc[4][4] = {};

    for (int k0 = 0; k0 < DM; k0 += 64) {
        __syncthreads();
        #pragma unroll
        for (int i = 0; i < 4; ++i) {
            const int e   = (i * 256 + tid) * 8;
            const int row = e >> 6;
            const int c   = ((e >> 3) & 7) ^ (row & 7);   // source-chunk swizzle
            async_cp16(A  + (size_t)(bm * 128 + row) * DM + k0 + c * 8, &Ash[e]);
            async_cp16(Bm + (size_t)(bn * 128 + row) * DM + k0 + c * 8, &Bsh[e]);
        }
        __syncthreads();

        #pragma unroll
        for (int ks = 0; ks < 2; ++ks) {
            bf16x8 af[4], bfr[4];
            #pragma unroll
            for (int mi = 0; mi < 4; ++mi) {
                const int row = wm * 64 + mi * 16 + l16;
                af[mi] = *(const bf16x8*)&Ash[row * 64 + (((ks * 4 + quad) ^ (l16 & 7)) << 3)];
            }
            #pragma unroll
            for (int ni = 0; ni < 4; ++ni) {
                const int row = wn * 64 + ni * 16 + l16;
                bfr[ni] = *(const bf16x8*)&Bsh[row * 64 + (((ks * 4 + quad) ^ (l16 & 7)) << 3)];
            }
            #pragma unroll
            for (int mi = 0; mi < 4; ++mi)
                #pragma unroll
                for (int ni = 0; ni < 4; ++ni)
                    acc[mi][ni] = mfma16x16x32(af[mi], bfr[ni], acc[mi][ni]);
        }
    }

    #pragma unroll
    for (int ni = 0; ni < 4; ++ni) {
        const int n    = bn * 128 + wn * 64 + ni * 16 + l16;
        const float bv_ = bias[n];
        const int h = n >> 6, d = n & 63;
        #pragma unroll
        for (int mi = 0; mi < 4; ++mi) {
            const int m0 = bm * 128 + wm * 64 + mi * 16 + quad * 4;
            const int b  = m0 >> 10;
            const int s0 = m0 & 1023;
            if (z == 2) {
                union { bf16 h4[4]; uint2 u; } pk;
                #pragma unroll
                for (int r = 0; r < 4; ++r) pk.h4[r] = (bf16)(acc[mi][ni][r] + bv_);
                *(uint2*)(vb + ((size_t)((b * NH + h) * DK + d)) * S_SZ + s0) = pk.u;
            } else {
                bf16* dst      = (z == 0) ? qb : kb;
                const float sc = (z == 0) ? 0.125f : 1.0f;
                #pragma unroll
                for (int r = 0; r < 4; ++r)
                    dst[((size_t)(b * NH + h) * S_SZ + (s0 + r)) * DK + d] =
                        (bf16)((acc[mi][ni][r] + bv_) * sc);
            }
        }
    }
}

// ---------------------------------------------------------------------------
// Kernel 2: attention — QBLK=32 per wave (128 q-rows/block, grid 128x8).
// Double-buffered 64-key K/V tiles (round-3 pipeline), 32 MFMA per tile per
// wave (2x round-3: K frags reused across both q-halves, V frags across both
// accumulators) with staged bytes / barriers / drains unchanged.
// ---------------------------------------------------------------------------
__global__ __launch_bounds__(256, 3)
void attn_kernel(const bf16* __restrict__ qb, const bf16* __restrict__ kb,
                 const bf16* __restrict__ vb, const bf16* __restrict__ gpb,
                 float* __restrict__ out)
{
    __shared__ bf16 Ksh[2][64 * 64];   // [key][dim], chunk-swizzled, 8 KB each
    __shared__ bf16 Vsh[2][64 * 64];   // [dim][key], chunk-swizzled, 8 KB each
    __shared__ bf16 Psh[4][32 * 72];   // per-wave P, [q][key], +8 pad
    __shared__ float Lsh[4][32];

    const int tid  = threadIdx.x;
    const int wid  = tid >> 6;
    const int lane = tid & 63;
    const int quad = lane >> 4;
    const int l16  = lane & 15;

    const int bh = blockIdx.x;
    const int qt = blockIdx.y;
    const int b  = bh >> 4;
    const int h  = bh & (NH - 1);
    const int q0 = qt * 128 + wid * 32;

    // Q as B-operand: qf[mq][kh] = Q[q0+mq*16+l16][kh*32+quad*8 ..]
    bf16x8 qf[2][2];
    #pragma unroll
    for (int mq = 0; mq < 2; ++mq) {
        const bf16* qr = qb + ((size_t)bh * S_SZ + q0 + mq * 16 + l16) * DK;
        qf[mq][0] = *(const bf16x8*)(qr + quad * 8);
        qf[mq][1] = *(const bf16x8*)(qr + 32 + quad * 8);
    }

    f32x4 acc[2][4] = {};       // acc[mq][ni]: q=mq*16+quad*4+r, d=ni*16+l16
    float lpart[2] = {};        // per q-half, q = mq*16+l16

    const bf16* gpq0 = gpb + ((size_t)b * S_SZ + q0 + l16) * S_SZ;   // mq=0 row
    const bf16* gpq1 = gpq0 + (size_t)16 * S_SZ;                     // mq=1 row
    const bf16* kbh = kb + (size_t)bh * (S_SZ * DK);
    const bf16* vbh = vb + (size_t)bh * ((size_t)DK * S_SZ);

    // stage tile t (keys t*64..+63) into buffer bufi (compile-time bufi)
    auto STAGE = [&](int t, int bufi) {
        #pragma unroll
        for (int i = 0; i < 2; ++i) {          // K: 64 x 64
            const int e   = (i * 256 + tid) * 8;
            const int row = e >> 6;
            const int c   = ((e >> 3) & 7) ^ (row & 7);
            async_cp16(kbh + (size_t)(t * 64 + row) * DK + c * 8, &Ksh[bufi][e]);
        }
        #pragma unroll
        for (int i = 0; i < 2; ++i) {          // V^T: 64 d x 64 keys
            const int e   = (i * 256 + tid) * 8;
            const int row = e >> 6;
            const int c   = ((e >> 3) & 7) ^ (row & 7);
            async_cp16(vbh + (size_t)row * S_SZ + t * 64 + c * 8, &Vsh[bufi][e]);
        }
    };
    auto GPLOAD = [&](int t, ushort4 (&g)[2][4]) {
        #pragma unroll
        for (int nb = 0; nb < 4; ++nb) {
            g[0][nb] = *(const ushort4*)(gpq0 + t * 64 + nb * 16 + quad * 4);
            g[1][nb] = *(const ushort4*)(gpq1 + t * 64 + nb * 16 + quad * 4);
        }
    };
    auto COMPUTE = [&](const bf16* Kb, const bf16* Vb, const ushort4 (&g)[2][4]) {
        // S^T = K Q^T per q-half; pack exp(s)*gp into Psh immediately
        #pragma unroll
        for (int nb = 0; nb < 4; ++nb) {
            const int row = nb * 16 + l16;
            const bf16x8 kf0 = *(const bf16x8*)&Kb[row * 64 + ((quad ^ (l16 & 7)) << 3)];
            const bf16x8 kf1 = *(const bf16x8*)&Kb[row * 64 + (((4 + quad) ^ (l16 & 7)) << 3)];
            #pragma unroll
            for (int mq = 0; mq < 2; ++mq) {
                f32x4 s = {0.0f, 0.0f, 0.0f, 0.0f};
                s = mfma16x16x32(kf0, qf[mq][0], s);
                s = mfma16x16x32(kf1, qf[mq][1], s);
                union { bf16 h4[4]; uint2 u; } pk;
                const unsigned short* gu = (const unsigned short*)&g[mq][nb];
                #pragma unroll
                for (int r = 0; r < 4; ++r) {
                    const float pv = __expf(s[r]);
                    lpart[mq] += pv;
                    const float gg = __uint_as_float(((unsigned)gu[r]) << 16);
                    pk.h4[r] = (bf16)(pv * gg);
                }
                *(uint2*)&Psh[wid][(mq * 16 + l16) * 72 + nb * 16 + quad * 4] = pk.u;
            }
        }
        // PV: A = P[q][k], B = V^T; vf reused across both q-halves
        bf16x8 pf[2][2];
        #pragma unroll
        for (int mq = 0; mq < 2; ++mq)
            #pragma unroll
            for (int j = 0; j < 2; ++j)
                pf[mq][j] = *(const bf16x8*)&Psh[wid][(mq * 16 + l16) * 72 + j * 32 + quad * 8];
        #pragma unroll
        for (int ni = 0; ni < 4; ++ni) {
            const int vrow = ni * 16 + l16;
            #pragma unroll
            for (int j = 0; j < 2; ++j) {
                const bf16x8 vf =
                    *(const bf16x8*)&Vb[vrow * 64 + (((j * 4 + quad) ^ (l16 & 7)) << 3)];
                #pragma unroll
                for (int mq = 0; mq < 2; ++mq)
                    acc[mq][ni] = mfma16x16x32(pf[mq][j], vf, acc[mq][ni]);
            }
        }
    };

    ushort4 gplA[2][4], gplB[2][4];
    STAGE(0, 0);
    GPLOAD(0, gplA);
    __syncthreads();                       // prologue drain (once)

    for (int tt = 0; tt < 8; ++tt) {
        const int t0 = tt * 2;
        // half A: prefetch t0+1 into buf1, compute t0 from buf0
        STAGE(t0 + 1, 1);
        GPLOAD(t0 + 1, gplB);
        COMPUTE(Ksh[0], Vsh[0], gplA);
        __syncthreads();                   // drain lands after compute overlap
        // half B: prefetch t0+2 into buf0, compute t0+1 from buf1
        if (t0 + 2 < 16) {
            STAGE(t0 + 2, 0);
            GPLOAD(t0 + 2, gplA);
        }
        COMPUTE(Ksh[1], Vsh[1], gplB);
        __syncthreads();
    }

    // denominator: sum across quads (keys), broadcast via LDS
    #pragma unroll
    for (int mq = 0; mq < 2; ++mq) {
        float lp = lpart[mq];
        lp += __shfl_xor(lp, 16, 64);
        lp += __shfl_xor(lp, 32, 64);
        if (quad == 0) Lsh[wid][mq * 16 + l16] = 1.0f / lp;
    }
    __syncthreads();

    #pragma unroll
    for (int mq = 0; mq < 2; ++mq) {
        #pragma unroll
        for (int r = 0; r < 4; ++r) {
            const float inv = Lsh[wid][mq * 16 + quad * 4 + r];
            float* orow = out + ((size_t)b * S_SZ + q0 + mq * 16 + quad * 4 + r) * DM + h * DK;
            #pragma unroll
            for (int ni = 0; ni < 4; ++ni)
                orow[ni * 16 + l16] = acc[mq][ni][r] * inv;
        }
    }
}

extern "C" void kernel_launch(void* const* d_in, const int* in_sizes, int n_in,
                              void* d_out, int out_size, void* d_ws, size_t ws_size,
                              hipStream_t stream) {
    const float* queries = (const float*)d_in[0];
    const float* keys    = (const float*)d_in[1];
    const float* values  = (const float*)d_in[2];
    const float* gp      = (const float*)d_in[3];
    // d_in[4] attention_mask: dead code in reference
    const float* Wq = (const float*)d_in[5];
    const float* bq = (const float*)d_in[6];
    const float* Wk = (const float*)d_in[7];
    const float* bk = (const float*)d_in[8];
    const float* Wv = (const float*)d_in[9];
    const float* bv = (const float*)d_in[10];
    float* out = (float*)d_out;

    // ws (bf16 elems): Xb 3x8M | Wb 3x1M | qb,kb,vb 3x8M. gpb reuses xb
    // (xb is dead after qkv_gemm; cvt_gp runs after it in stream order).
    bf16* xb = (bf16*)d_ws;
    bf16* wb = xb + (size_t)3 * 8 * 1024 * 1024;
    bf16* qb = wb + (size_t)3 * 1024 * 1024;
    bf16* kb = qb + (size_t)B_SZ * NH * S_SZ * DK;
    bf16* vb = kb + (size_t)B_SZ * NH * S_SZ * DK;
    bf16* gpb = xb;
    (void)ws_size; (void)in_sizes; (void)n_in; (void)out_size;

    dim3 gc(4096, 6);
    cvt_kernel<<<gc, 256, 0, stream>>>(queries, keys, values, Wq, Wk, Wv, xb, wb);

    dim3 g1(64, 8, 3);
    qkv_gemm<<<g1, 256, 0, stream>>>(xb, wb, bq, bk, bv, qb, kb, vb);

    cvt_gp_kernel<<<dim3(4096), 256, 0, stream>>>(gp, gpb);

    dim3 g2(B_SZ * NH /*128*/, S_SZ / 128 /*8*/, 1);
    attn_kernel<<<g2, 256, 0, stream>>>(qb, kb, vb, gpb, out);
}

// Round 5
// 349.972 us; speedup vs baseline: 1.2317x; 1.0080x over previous
//
#include <hip/hip_runtime.h>

#define B_SZ 8
#define S_SZ 1024
#define DM   1024
#define NH   16
#define DK   64

typedef __bf16 bf16;
typedef __bf16 bf16x8 __attribute__((ext_vector_type(8)));
typedef float  f32x4  __attribute__((ext_vector_type(4)));

__device__ __forceinline__ f32x4 mfma16x16x32(bf16x8 a, bf16x8 b, f32x4 c) {
    return __builtin_amdgcn_mfma_f32_16x16x32_bf16(a, b, c, 0, 0, 0);
}

typedef const __attribute__((address_space(1))) void* gptr_t;
typedef __attribute__((address_space(3))) void*       sptr_t;
__device__ __forceinline__ void async_cp16(const void* g, void* s) {
    __builtin_amdgcn_global_load_lds((gptr_t)g, (sptr_t)s, 16, 0, 0);
}

// ---------------------------------------------------------------------------
// Kernel 0: fp32 -> bf16 convert for X (z<3) and W (z>=3).
// ---------------------------------------------------------------------------
__global__ __launch_bounds__(256)
void cvt_kernel(const float* __restrict__ x0, const float* __restrict__ x1,
                const float* __restrict__ x2, const float* __restrict__ w0,
                const float* __restrict__ w1, const float* __restrict__ w2,
                bf16* __restrict__ xb, bf16* __restrict__ wb)
{
    const int z = blockIdx.y;
    const float* src;
    bf16* dst;
    int n;
    if (z < 3) {
        src = (z == 0) ? x0 : (z == 1) ? x1 : x2;
        dst = xb + (size_t)z * (8u * 1024 * 1024);
        n = 8 * 1024 * 1024;
    } else {
        const int w = z - 3;
        src = (w == 0) ? w0 : (w == 1) ? w1 : w2;
        dst = wb + (size_t)w * (1024 * 1024);
        n = 1024 * 1024;
    }
    const int idx = (blockIdx.x * 256 + threadIdx.x) * 8;
    if (idx >= n) return;
    const float4 a = *(const float4*)(src + idx);
    const float4 c = *(const float4*)(src + idx + 4);
    union { bf16 h[8]; uint4 u; } pk;
    pk.h[0] = (bf16)a.x; pk.h[1] = (bf16)a.y; pk.h[2] = (bf16)a.z; pk.h[3] = (bf16)a.w;
    pk.h[4] = (bf16)c.x; pk.h[5] = (bf16)c.y; pk.h[6] = (bf16)c.z; pk.h[7] = (bf16)c.w;
    *(uint4*)(dst + idx) = pk.u;
}

// gp fp32 -> bf16 (runs AFTER qkv_gemm; output aliases the dead xb region)
__global__ __launch_bounds__(256)
void cvt_gp_kernel(const float* __restrict__ gp, bf16* __restrict__ gpb)
{
    const int idx = (blockIdx.x * 256 + threadIdx.x) * 8;
    const float4 a = *(const float4*)(gp + idx);
    const float4 c = *(const float4*)(gp + idx + 4);
    union { bf16 h[8]; uint4 u; } pk;
    pk.h[0] = (bf16)a.x; pk.h[1] = (bf16)a.y; pk.h[2] = (bf16)a.z; pk.h[3] = (bf16)a.w;
    pk.h[4] = (bf16)c.x; pk.h[5] = (bf16)c.y; pk.h[6] = (bf16)c.z; pk.h[7] = (bf16)c.w;
    *(uint4*)(gpb + idx) = pk.u;
}

// ---------------------------------------------------------------------------
// Kernel 1: m97-style bf16 GEMM with XOR chunk-swizzled LDS (unchanged).
// ---------------------------------------------------------------------------
__global__ __launch_bounds__(256, 2)
void qkv_gemm(const bf16* __restrict__ xb, const bf16* __restrict__ wb,
              const float* __restrict__ bq, const float* __restrict__ bk,
              const float* __restrict__ bv,
              bf16* __restrict__ qb, bf16* __restrict__ kb,
              bf16* __restrict__ vb)
{
    const int z = blockIdx.z;
    const bf16* A  = xb + (size_t)z * (8u * 1024 * 1024);
    const bf16* Bm = wb + (size_t)z * (1024 * 1024);
    const float* bias = (z == 0) ? bq : (z == 1) ? bk : bv;

    __shared__ bf16 Ash[128 * 64];
    __shared__ bf16 Bsh[128 * 64];

    const int tid  = threadIdx.x;
    const int wid  = tid >> 6;
    const int lane = tid & 63;
    const int quad = lane >> 4;
    const int l16  = lane & 15;
    const int wm   = wid >> 1, wn = wid & 1;
    const int bm   = blockIdx.x, bn = blockIdx.y;

    f32x4 acc[4][4] = {};

    for (int k0 = 0; k0 < DM; k0 += 64) {
        __syncthreads();
        #pragma unroll
        for (int i = 0; i < 4; ++i) {
            const int e   = (i * 256 + tid) * 8;
            const int row = e >> 6;
            const int c   = ((e >> 3) & 7) ^ (row & 7);   // source-chunk swizzle
            async_cp16(A  + (size_t)(bm * 128 + row) * DM + k0 + c * 8, &Ash[e]);
            async_cp16(Bm + (size_t)(bn * 128 + row) * DM + k0 + c * 8, &Bsh[e]);
        }
        __syncthreads();

        #pragma unroll
        for (int ks = 0; ks < 2; ++ks) {
            bf16x8 af[4], bfr[4];
            #pragma unroll
            for (int mi = 0; mi < 4; ++mi) {
                const int row = wm * 64 + mi * 16 + l16;
                af[mi] = *(const bf16x8*)&Ash[row * 64 + (((ks * 4 + quad) ^ (l16 & 7)) << 3)];
            }
            #pragma unroll
            for (int ni = 0; ni < 4; ++ni) {
                const int row = wn * 64 + ni * 16 + l16;
                bfr[ni] = *(const bf16x8*)&Bsh[row * 64 + (((ks * 4 + quad) ^ (l16 & 7)) << 3)];
            }
            #pragma unroll
            for (int mi = 0; mi < 4; ++mi)
                #pragma unroll
                for (int ni = 0; ni < 4; ++ni)
                    acc[mi][ni] = mfma16x16x32(af[mi], bfr[ni], acc[mi][ni]);
        }
    }

    #pragma unroll
    for (int ni = 0; ni < 4; ++ni) {
        const int n    = bn * 128 + wn * 64 + ni * 16 + l16;
        const float bv_ = bias[n];
        const int h = n >> 6, d = n & 63;
        #pragma unroll
        for (int mi = 0; mi < 4; ++mi) {
            const int m0 = bm * 128 + wm * 64 + mi * 16 + quad * 4;
            const int b  = m0 >> 10;
            const int s0 = m0 & 1023;
            if (z == 2) {
                union { bf16 h4[4]; uint2 u; } pk;
                #pragma unroll
                for (int r = 0; r < 4; ++r) pk.h4[r] = (bf16)(acc[mi][ni][r] + bv_);
                *(uint2*)(vb + ((size_t)((b * NH + h) * DK + d)) * S_SZ + s0) = pk.u;
            } else {
                bf16* dst      = (z == 0) ? qb : kb;
                const float sc = (z == 0) ? 0.125f : 1.0f;
                #pragma unroll
                for (int r = 0; r < 4; ++r)
                    dst[((size_t)(b * NH + h) * S_SZ + (s0 + r)) * DK + d] =
                        (bf16)((acc[mi][ni][r] + bv_) * sc);
            }
        }
    }
}

// ---------------------------------------------------------------------------
// Kernel 2: attention — 8-wave (512-thread) blocks, QBLK=16 per wave.
// Same per-wave structure as round-3 (verified), but 8 waves share the
// double-buffered K/V staging: staging bytes and barriers unchanged while
// resident waves/CU double (12 -> 24, LDS-capped at 3 blocks/CU).
// ---------------------------------------------------------------------------
__global__ __launch_bounds__(512, 6)
void attn_kernel(const bf16* __restrict__ qb, const bf16* __restrict__ kb,
                 const bf16* __restrict__ vb, const bf16* __restrict__ gpb,
                 float* __restrict__ out)
{
    __shared__ bf16 Ksh[2][64 * 64];   // [key][dim], chunk-swizzled, 8 KB each
    __shared__ bf16 Vsh[2][64 * 64];   // [dim][key], chunk-swizzled, 8 KB each
    __shared__ bf16 Psh[8][16 * 72];   // per-wave P, [q][key], +8 pad
    __shared__ float Lsh[8][16];

    const int tid  = threadIdx.x;
    const int wid  = tid >> 6;         // 0..7
    const int lane = tid & 63;
    const int quad = lane >> 4;
    const int l16  = lane & 15;

    const int bh = blockIdx.x;
    const int qt = blockIdx.y;
    const int b  = bh >> 4;
    const int h  = bh & (NH - 1);
    const int q0 = qt * 128 + wid * 16;

    // Q as B-operand: B[k=d][n=q]: lane l16 -> q, quad*8+j -> d
    const bf16* qr = qb + ((size_t)bh * S_SZ + q0 + l16) * DK;
    const bf16x8 qf0 = *(const bf16x8*)(qr + quad * 8);
    const bf16x8 qf1 = *(const bf16x8*)(qr + 32 + quad * 8);

    f32x4 acc[4] = {};
    float lpart = 0.0f;

    const bf16* gpq = gpb + ((size_t)b * S_SZ + q0 + l16) * S_SZ;  // gp row q
    const bf16* kbh = kb + (size_t)bh * (S_SZ * DK);
    const bf16* vbh = vb + (size_t)bh * ((size_t)DK * S_SZ);

    // stage tile t (keys t*64..+63) into buffer bufi; 512 threads -> 1 chunk
    // of K and 1 chunk of V each (64x64 bf16 = 512 x 16B).
    auto STAGE = [&](int t, int bufi) {
        const int e   = tid * 8;               // elements, 0..4088
        const int row = e >> 6;
        const int c   = ((e >> 3) & 7) ^ (row & 7);
        async_cp16(kbh + (size_t)(t * 64 + row) * DK + c * 8, &Ksh[bufi][e]);
        async_cp16(vbh + (size_t)row * S_SZ + t * 64 + c * 8, &Vsh[bufi][e]);
    };
    auto GPLOAD = [&](int t, ushort4 (&g)[4]) {
        #pragma unroll
        for (int nb = 0; nb < 4; ++nb)
            g[nb] = *(const ushort4*)(gpq + t * 64 + nb * 16 + quad * 4);
    };
    auto COMPUTE = [&](const bf16* Kb, const bf16* Vb, const ushort4 (&g)[4]) {
        // S^T = K Q^T: lane holds key = nb*16+quad*4+r, q = l16
        f32x4 sc[4];
        #pragma unroll
        for (int nb = 0; nb < 4; ++nb) {
            const int row = nb * 16 + l16;
            const bf16x8 kf0 = *(const bf16x8*)&Kb[row * 64 + ((quad ^ (l16 & 7)) << 3)];
            const bf16x8 kf1 = *(const bf16x8*)&Kb[row * 64 + (((4 + quad) ^ (l16 & 7)) << 3)];
            f32x4 s = {0.0f, 0.0f, 0.0f, 0.0f};
            s = mfma16x16x32(kf0, qf0, s);
            s = mfma16x16x32(kf1, qf1, s);
            sc[nb] = s;
        }
        // p = exp(s), denominator partial, P*gp -> Psh packed
        #pragma unroll
        for (int nb = 0; nb < 4; ++nb) {
            union { bf16 h4[4]; uint2 u; } pk;
            const unsigned short* gu = (const unsigned short*)&g[nb];
            #pragma unroll
            for (int r = 0; r < 4; ++r) {
                const float pv = __expf(sc[nb][r]);
                lpart += pv;
                const float gg = __uint_as_float(((unsigned)gu[r]) << 16);
                pk.h4[r] = (bf16)(pv * gg);
            }
            *(uint2*)&Psh[wid][l16 * 72 + nb * 16 + quad * 4] = pk.u;
        }
        // PV: A = P[q=l16][k], B = V^T
        bf16x8 pf[2];
        #pragma unroll
        for (int j = 0; j < 2; ++j)
            pf[j] = *(const bf16x8*)&Psh[wid][l16 * 72 + j * 32 + quad * 8];
        #pragma unroll
        for (int ni = 0; ni < 4; ++ni) {
            const int vrow = ni * 16 + l16;
            #pragma unroll
            for (int j = 0; j < 2; ++j) {
                const bf16x8 vf =
                    *(const bf16x8*)&Vb[vrow * 64 + (((j * 4 + quad) ^ (l16 & 7)) << 3)];
                acc[ni] = mfma16x16x32(pf[j], vf, acc[ni]);
            }
        }
    };

    ushort4 gplA[4], gplB[4];
    STAGE(0, 0);
    GPLOAD(0, gplA);
    __syncthreads();                       // prologue drain (once)

    for (int tt = 0; tt < 8; ++tt) {
        const int t0 = tt * 2;
        // half A: prefetch t0+1 into buf1, compute t0 from buf0
        STAGE(t0 + 1, 1);
        GPLOAD(t0 + 1, gplB);
        COMPUTE(Ksh[0], Vsh[0], gplA);
        __syncthreads();                   // drain lands after compute overlap
        // half B: prefetch t0+2 into buf0, compute t0+1 from buf1
        if (t0 + 2 < 16) {
            STAGE(t0 + 2, 0);
            GPLOAD(t0 + 2, gplA);
        }
        COMPUTE(Ksh[1], Vsh[1], gplB);
        __syncthreads();
    }

    // denominator: sum across quads (keys), broadcast via LDS
    lpart += __shfl_xor(lpart, 16, 64);
    lpart += __shfl_xor(lpart, 32, 64);
    if (quad == 0) Lsh[wid][l16] = 1.0f / lpart;
    __syncthreads();

    #pragma unroll
    for (int r = 0; r < 4; ++r) {
        const float inv = Lsh[wid][quad * 4 + r];
        float* orow = out + ((size_t)b * S_SZ + q0 + quad * 4 + r) * DM + h * DK;
        #pragma unroll
        for (int ni = 0; ni < 4; ++ni)
            orow[ni * 16 + l16] = acc[ni][r] * inv;
    }
}

extern "C" void kernel_launch(void* const* d_in, const int* in_sizes, int n_in,
                              void* d_out, int out_size, void* d_ws, size_t ws_size,
                              hipStream_t stream) {
    const float* queries = (const float*)d_in[0];
    const float* keys    = (const float*)d_in[1];
    const float* values  = (const float*)d_in[2];
    const float* gp      = (const float*)d_in[3];
    // d_in[4] attention_mask: dead code in reference
    const float* Wq = (const float*)d_in[5];
    const float* bq = (const float*)d_in[6];
    const float* Wk = (const float*)d_in[7];
    const float* bk = (const float*)d_in[8];
    const float* Wv = (const float*)d_in[9];
    const float* bv = (const float*)d_in[10];
    float* out = (float*)d_out;

    // ws (bf16 elems): Xb 3x8M | Wb 3x1M | qb,kb,vb 3x8M. gpb reuses xb
    // (xb is dead after qkv_gemm; cvt_gp runs after it in stream order).
    bf16* xb = (bf16*)d_ws;
    bf16* wb = xb + (size_t)3 * 8 * 1024 * 1024;
    bf16* qb = wb + (size_t)3 * 1024 * 1024;
    bf16* kb = qb + (size_t)B_SZ * NH * S_SZ * DK;
    bf16* vb = kb + (size_t)B_SZ * NH * S_SZ * DK;
    bf16* gpb = xb;
    (void)ws_size; (void)in_sizes; (void)n_in; (void)out_size;

    dim3 gc(4096, 6);
    cvt_kernel<<<gc, 256, 0, stream>>>(queries, keys, values, Wq, Wk, Wv, xb, wb);

    dim3 g1(64, 8, 3);
    qkv_gemm<<<g1, 256, 0, stream>>>(xb, wb, bq, bk, bv, qb, kb, vb);

    cvt_gp_kernel<<<dim3(4096), 256, 0, stream>>>(gp, gpb);

    dim3 g2(B_SZ * NH /*128*/, S_SZ / 128 /*8*/, 1);
    attn_kernel<<<g2, 512, 0, stream>>>(qb, kb, vb, gpb, out);
}

// Round 6
// 332.529 us; speedup vs baseline: 1.2964x; 1.0525x over previous
//
#include <hip/hip_runtime.h>

#define B_SZ 8
#define S_SZ 1024
#define DM   1024
#define NH   16
#define DK   64

typedef __bf16 bf16;
typedef __bf16 bf16x8 __attribute__((ext_vector_type(8)));
typedef float  f32x4  __attribute__((ext_vector_type(4)));

__device__ __forceinline__ f32x4 mfma16x16x32(bf16x8 a, bf16x8 b, f32x4 c) {
    return __builtin_amdgcn_mfma_f32_16x16x32_bf16(a, b, c, 0, 0, 0);
}

typedef const __attribute__((address_space(1))) void* gptr_t;
typedef __attribute__((address_space(3))) void*       sptr_t;
__device__ __forceinline__ void async_cp16(const void* g, void* s) {
    __builtin_amdgcn_global_load_lds((gptr_t)g, (sptr_t)s, 16, 0, 0);
}

// ---------------------------------------------------------------------------
// Kernel 0: fp32 -> bf16 convert for X (z<3) and W (z>=3).
// ---------------------------------------------------------------------------
__global__ __launch_bounds__(256)
void cvt_kernel(const float* __restrict__ x0, const float* __restrict__ x1,
                const float* __restrict__ x2, const float* __restrict__ w0,
                const float* __restrict__ w1, const float* __restrict__ w2,
                bf16* __restrict__ xb, bf16* __restrict__ wb)
{
    const int z = blockIdx.y;
    const float* src;
    bf16* dst;
    int n;
    if (z < 3) {
        src = (z == 0) ? x0 : (z == 1) ? x1 : x2;
        dst = xb + (size_t)z * (8u * 1024 * 1024);
        n = 8 * 1024 * 1024;
    } else {
        const int w = z - 3;
        src = (w == 0) ? w0 : (w == 1) ? w1 : w2;
        dst = wb + (size_t)w * (1024 * 1024);
        n = 1024 * 1024;
    }
    const int idx = (blockIdx.x * 256 + threadIdx.x) * 8;
    if (idx >= n) return;
    const float4 a = *(const float4*)(src + idx);
    const float4 c = *(const float4*)(src + idx + 4);
    union { bf16 h[8]; uint4 u; } pk;
    pk.h[0] = (bf16)a.x; pk.h[1] = (bf16)a.y; pk.h[2] = (bf16)a.z; pk.h[3] = (bf16)a.w;
    pk.h[4] = (bf16)c.x; pk.h[5] = (bf16)c.y; pk.h[6] = (bf16)c.z; pk.h[7] = (bf16)c.w;
    *(uint4*)(dst + idx) = pk.u;
}

// gp fp32 -> bf16 (runs AFTER qkv_gemm; output aliases the dead xb region)
__global__ __launch_bounds__(256)
void cvt_gp_kernel(const float* __restrict__ gp, bf16* __restrict__ gpb)
{
    const int idx = (blockIdx.x * 256 + threadIdx.x) * 8;
    const float4 a = *(const float4*)(gp + idx);
    const float4 c = *(const float4*)(gp + idx + 4);
    union { bf16 h[8]; uint4 u; } pk;
    pk.h[0] = (bf16)a.x; pk.h[1] = (bf16)a.y; pk.h[2] = (bf16)a.z; pk.h[3] = (bf16)a.w;
    pk.h[4] = (bf16)c.x; pk.h[5] = (bf16)c.y; pk.h[6] = (bf16)c.z; pk.h[7] = (bf16)c.w;
    *(uint4*)(gpb + idx) = pk.u;
}

// ---------------------------------------------------------------------------
// Kernel 1: m97-style bf16 GEMM with XOR chunk-swizzled LDS (unchanged).
// ---------------------------------------------------------------------------
__global__ __launch_bounds__(256, 2)
void qkv_gemm(const bf16* __restrict__ xb, const bf16* __restrict__ wb,
              const float* __restrict__ bq, const float* __restrict__ bk,
              const float* __restrict__ bv,
              bf16* __restrict__ qb, bf16* __restrict__ kb,
              bf16* __restrict__ vb)
{
    const int z = blockIdx.z;
    const bf16* A  = xb + (size_t)z * (8u * 1024 * 1024);
    const bf16* Bm = wb + (size_t)z * (1024 * 1024);
    const float* bias = (z == 0) ? bq : (z == 1) ? bk : bv;

    __shared__ bf16 Ash[128 * 64];
    __shared__ bf16 Bsh[128 * 64];

    const int tid  = threadIdx.x;
    const int wid  = tid >> 6;
    const int lane = tid & 63;
    const int quad = lane >> 4;
    const int l16  = lane & 15;
    const int wm   = wid >> 1, wn = wid & 1;
    const int bm   = blockIdx.x, bn = blockIdx.y;

    f32x4 acc[4][4] = {};

    for (int k0 = 0; k0 < DM; k0 += 64) {
        __syncthreads();
        #pragma unroll
        for (int i = 0; i < 4; ++i) {
            const int e   = (i * 256 + tid) * 8;
            const int row = e >> 6;
            const int c   = ((e >> 3) & 7) ^ (row & 7);   // source-chunk swizzle
            async_cp16(A  + (size_t)(bm * 128 + row) * DM + k0 + c * 8, &Ash[e]);
            async_cp16(Bm + (size_t)(bn * 128 + row) * DM + k0 + c * 8, &Bsh[e]);
        }
        __syncthreads();

        #pragma unroll
        for (int ks = 0; ks < 2; ++ks) {
            bf16x8 af[4], bfr[4];
            #pragma unroll
            for (int mi = 0; mi < 4; ++mi) {
                const int row = wm * 64 + mi * 16 + l16;
                af[mi] = *(const bf16x8*)&Ash[row * 64 + (((ks * 4 + quad) ^ (l16 & 7)) << 3)];
            }
            #pragma unroll
            for (int ni = 0; ni < 4; ++ni) {
                const int row = wn * 64 + ni * 16 + l16;
                bfr[ni] = *(const bf16x8*)&Bsh[row * 64 + (((ks * 4 + quad) ^ (l16 & 7)) << 3)];
            }
            #pragma unroll
            for (int mi = 0; mi < 4; ++mi)
                #pragma unroll
                for (int ni = 0; ni < 4; ++ni)
                    acc[mi][ni] = mfma16x16x32(af[mi], bfr[ni], acc[mi][ni]);
        }
    }

    #pragma unroll
    for (int ni = 0; ni < 4; ++ni) {
        const int n    = bn * 128 + wn * 64 + ni * 16 + l16;
        const float bv_ = bias[n];
        const int h = n >> 6, d = n & 63;
        #pragma unroll
        for (int mi = 0; mi < 4; ++mi) {
            const int m0 = bm * 128 + wm * 64 + mi * 16 + quad * 4;
            const int b  = m0 >> 10;
            const int s0 = m0 & 1023;
            if (z == 2) {
                union { bf16 h4[4]; uint2 u; } pk;
                #pragma unroll
                for (int r = 0; r < 4; ++r) pk.h4[r] = (bf16)(acc[mi][ni][r] + bv_);
                *(uint2*)(vb + ((size_t)((b * NH + h) * DK + d)) * S_SZ + s0) = pk.u;
            } else {
                bf16* dst      = (z == 0) ? qb : kb;
                const float sc = (z == 0) ? 0.125f : 1.0f;
                #pragma unroll
                for (int r = 0; r < 4; ++r)
                    dst[((size_t)(b * NH + h) * S_SZ + (s0 + r)) * DK + d] =
                        (bf16)((acc[mi][ni][r] + bv_) * sc);
            }
        }
    }
}

// ---------------------------------------------------------------------------
// Kernel 2: attention — 8-wave blocks (round-5 structure, verified) + XCD-
// locality remap: (b,h,qt) derived from flat block id so b = lid%8 = XCD.
// All 16 head-blocks sharing a (b,qt) gp slice land on ONE XCD, 8 ids apart
// -> gp fetched from HBM once per XCD instead of ~8x (gp was ~all of FETCH).
// K/V reuse across qt also stays XCD-local (spacing 128 = 0 mod 8).
// ---------------------------------------------------------------------------
__global__ __launch_bounds__(512, 6)
void attn_kernel(const bf16* __restrict__ qb, const bf16* __restrict__ kb,
                 const bf16* __restrict__ vb, const bf16* __restrict__ gpb,
                 float* __restrict__ out)
{
    __shared__ bf16 Ksh[2][64 * 64];   // [key][dim], chunk-swizzled, 8 KB each
    __shared__ bf16 Vsh[2][64 * 64];   // [dim][key], chunk-swizzled, 8 KB each
    __shared__ bf16 Psh[8][16 * 72];   // per-wave P, [q][key], +8 pad
    __shared__ float Lsh[8][16];

    const int tid  = threadIdx.x;
    const int wid  = tid >> 6;         // 0..7
    const int lane = tid & 63;
    const int quad = lane >> 4;
    const int l16  = lane & 15;

    // XCD-locality remap (bijective over 1024 blocks):
    //   b = lid&7 (== XCD under linear round-robin), h = (lid>>3)&15, qt = lid>>7
    const int lid = blockIdx.x + (int)gridDim.x * blockIdx.y;
    const int b   = lid & 7;
    const int h   = (lid >> 3) & (NH - 1);
    const int qt  = lid >> 7;
    const int bh  = b * NH + h;
    const int q0  = qt * 128 + wid * 16;

    // Q as B-operand: B[k=d][n=q]: lane l16 -> q, quad*8+j -> d
    const bf16* qr = qb + ((size_t)bh * S_SZ + q0 + l16) * DK;
    const bf16x8 qf0 = *(const bf16x8*)(qr + quad * 8);
    const bf16x8 qf1 = *(const bf16x8*)(qr + 32 + quad * 8);

    f32x4 acc[4] = {};
    float lpart = 0.0f;

    const bf16* gpq = gpb + ((size_t)b * S_SZ + q0 + l16) * S_SZ;  // gp row q
    const bf16* kbh = kb + (size_t)bh * (S_SZ * DK);
    const bf16* vbh = vb + (size_t)bh * ((size_t)DK * S_SZ);

    // stage tile t (keys t*64..+63) into buffer bufi; 512 threads -> 1 chunk
    // of K and 1 chunk of V each (64x64 bf16 = 512 x 16B).
    auto STAGE = [&](int t, int bufi) {
        const int e   = tid * 8;               // elements, 0..4088
        const int row = e >> 6;
        const int c   = ((e >> 3) & 7) ^ (row & 7);
        async_cp16(kbh + (size_t)(t * 64 + row) * DK + c * 8, &Ksh[bufi][e]);
        async_cp16(vbh + (size_t)row * S_SZ + t * 64 + c * 8, &Vsh[bufi][e]);
    };
    auto GPLOAD = [&](int t, ushort4 (&g)[4]) {
        #pragma unroll
        for (int nb = 0; nb < 4; ++nb)
            g[nb] = *(const ushort4*)(gpq + t * 64 + nb * 16 + quad * 4);
    };
    auto COMPUTE = [&](const bf16* Kb, const bf16* Vb, const ushort4 (&g)[4]) {
        // S^T = K Q^T: lane holds key = nb*16+quad*4+r, q = l16
        f32x4 sc[4];
        #pragma unroll
        for (int nb = 0; nb < 4; ++nb) {
            const int row = nb * 16 + l16;
            const bf16x8 kf0 = *(const bf16x8*)&Kb[row * 64 + ((quad ^ (l16 & 7)) << 3)];
            const bf16x8 kf1 = *(const bf16x8*)&Kb[row * 64 + (((4 + quad) ^ (l16 & 7)) << 3)];
            f32x4 s = {0.0f, 0.0f, 0.0f, 0.0f};
            s = mfma16x16x32(kf0, qf0, s);
            s = mfma16x16x32(kf1, qf1, s);
            sc[nb] = s;
        }
        // p = exp(s), denominator partial, P*gp -> Psh packed
        #pragma unroll
        for (int nb = 0; nb < 4; ++nb) {
            union { bf16 h4[4]; uint2 u; } pk;
            const unsigned short* gu = (const unsigned short*)&g[nb];
            #pragma unroll
            for (int r = 0; r < 4; ++r) {
                const float pv = __expf(sc[nb][r]);
                lpart += pv;
                const float gg = __uint_as_float(((unsigned)gu[r]) << 16);
                pk.h4[r] = (bf16)(pv * gg);
            }
            *(uint2*)&Psh[wid][l16 * 72 + nb * 16 + quad * 4] = pk.u;
        }
        // PV: A = P[q=l16][k], B = V^T
        bf16x8 pf[2];
        #pragma unroll
        for (int j = 0; j < 2; ++j)
            pf[j] = *(const bf16x8*)&Psh[wid][l16 * 72 + j * 32 + quad * 8];
        #pragma unroll
        for (int ni = 0; ni < 4; ++ni) {
            const int vrow = ni * 16 + l16;
            #pragma unroll
            for (int j = 0; j < 2; ++j) {
                const bf16x8 vf =
                    *(const bf16x8*)&Vb[vrow * 64 + (((j * 4 + quad) ^ (l16 & 7)) << 3)];
                acc[ni] = mfma16x16x32(pf[j], vf, acc[ni]);
            }
        }
    };

    ushort4 gplA[4], gplB[4];
    STAGE(0, 0);
    GPLOAD(0, gplA);
    __syncthreads();                       // prologue drain (once)

    for (int tt = 0; tt < 8; ++tt) {
        const int t0 = tt * 2;
        // half A: prefetch t0+1 into buf1, compute t0 from buf0
        STAGE(t0 + 1, 1);
        GPLOAD(t0 + 1, gplB);
        COMPUTE(Ksh[0], Vsh[0], gplA);
        __syncthreads();                   // drain lands after compute overlap
        // half B: prefetch t0+2 into buf0, compute t0+1 from buf1
        if (t0 + 2 < 16) {
            STAGE(t0 + 2, 0);
            GPLOAD(t0 + 2, gplA);
        }
        COMPUTE(Ksh[1], Vsh[1], gplB);
        __syncthreads();
    }

    // denominator: sum across quads (keys), broadcast via LDS
    lpart += __shfl_xor(lpart, 16, 64);
    lpart += __shfl_xor(lpart, 32, 64);
    if (quad == 0) Lsh[wid][l16] = 1.0f / lpart;
    __syncthreads();

    #pragma unroll
    for (int r = 0; r < 4; ++r) {
        const float inv = Lsh[wid][quad * 4 + r];
        float* orow = out + ((size_t)b * S_SZ + q0 + quad * 4 + r) * DM + h * DK;
        #pragma unroll
        for (int ni = 0; ni < 4; ++ni)
            orow[ni * 16 + l16] = acc[ni][r] * inv;
    }
}

extern "C" void kernel_launch(void* const* d_in, const int* in_sizes, int n_in,
                              void* d_out, int out_size, void* d_ws, size_t ws_size,
                              hipStream_t stream) {
    const float* queries = (const float*)d_in[0];
    const float* keys    = (const float*)d_in[1];
    const float* values  = (const float*)d_in[2];
    const float* gp      = (const float*)d_in[3];
    // d_in[4] attention_mask: dead code in reference
    const float* Wq = (const float*)d_in[5];
    const float* bq = (const float*)d_in[6];
    const float* Wk = (const float*)d_in[7];
    const float* bk = (const float*)d_in[8];
    const float* Wv = (const float*)d_in[9];
    const float* bv = (const float*)d_in[10];
    float* out = (float*)d_out;

    // ws (bf16 elems): Xb 3x8M | Wb 3x1M | qb,kb,vb 3x8M. gpb reuses xb
    // (xb is dead after qkv_gemm; cvt_gp runs after it in stream order).
    bf16* xb = (bf16*)d_ws;
    bf16* wb = xb + (size_t)3 * 8 * 1024 * 1024;
    bf16* qb = wb + (size_t)3 * 1024 * 1024;
    bf16* kb = qb + (size_t)B_SZ * NH * S_SZ * DK;
    bf16* vb = kb + (size_t)B_SZ * NH * S_SZ * DK;
    bf16* gpb = xb;
    (void)ws_size; (void)in_sizes; (void)n_in; (void)out_size;

    dim3 gc(4096, 6);
    cvt_kernel<<<gc, 256, 0, stream>>>(queries, keys, values, Wq, Wk, Wv, xb, wb);

    dim3 g1(64, 8, 3);
    qkv_gemm<<<g1, 256, 0, stream>>>(xb, wb, bq, bk, bv, qb, kb, vb);

    cvt_gp_kernel<<<dim3(4096), 256, 0, stream>>>(gp, gpb);

    dim3 g2(B_SZ * NH /*128*/, S_SZ / 128 /*8*/, 1);
    attn_kernel<<<g2, 512, 0, stream>>>(qb, kb, vb, gpb, out);
}